// Round 7
// baseline (5680.023 us; speedup 1.0000x reference)
//
#include <hip/hip_runtime.h>
#include <hip/hip_cooperative_groups.h>

namespace cg = cooperative_groups;

#define T_STEPS 64
#define BATCH   128
#define HID     1024
#define H3      3072
#define EMBD    1024
#define SLEN    128
#define BH      (BATCH * HID)

typedef __attribute__((ext_vector_type(8))) short short8;
typedef __attribute__((ext_vector_type(4))) float f32x4;

__device__ __forceinline__ unsigned short f2bf(float x) {
    unsigned int u = __float_as_uint(x);
    unsigned int r = (u + 0x7fffu + ((u >> 16) & 1u)) >> 16;
    return (unsigned short)r;
}
__device__ __forceinline__ float bf2f(unsigned short h) {
    return __uint_as_float(((unsigned int)h) << 16);
}
__device__ __forceinline__ unsigned int pk(unsigned short a, unsigned short b) {
    return (unsigned int)a | ((unsigned int)b << 16);
}
__device__ __forceinline__ void cvt8(const float4& x, const float4& y,
                                     uint4& H, uint4& L) {
    unsigned short h0 = f2bf(x.x), h1 = f2bf(x.y), h2 = f2bf(x.z), h3 = f2bf(x.w);
    unsigned short h4 = f2bf(y.x), h5 = f2bf(y.y), h6 = f2bf(y.z), h7 = f2bf(y.w);
    unsigned short l0 = f2bf(x.x - bf2f(h0)), l1 = f2bf(x.y - bf2f(h1));
    unsigned short l2 = f2bf(x.z - bf2f(h2)), l3 = f2bf(x.w - bf2f(h3));
    unsigned short l4 = f2bf(y.x - bf2f(h4)), l5 = f2bf(y.y - bf2f(h5));
    unsigned short l6 = f2bf(y.z - bf2f(h6)), l7 = f2bf(y.w - bf2f(h7));
    H = make_uint4(pk(h0,h1), pk(h2,h3), pk(h4,h5), pk(h6,h7));
    L = make_uint4(pk(l0,l1), pk(l2,l3), pk(l4,l5), pk(l6,l7));
}
__device__ __forceinline__ float sigf(float x) {
    return 1.f / (1.f + __expf(-x));
}

#define MF(A, B, ACC) ACC = __builtin_amdgcn_mfma_f32_16x16x32_bf16(A, B, ACC, 0, 0, 0)
#define TRI(AH, AL, WH, WL, ACC)  MF(AH, WL, ACC); MF(AL, WH, ACC); MF(AH, WH, ACC);

// ============== plane-conversion kernels (run once per call) ==============
__global__ __launch_bounds__(256) void conv_planes_k(
    const float* __restrict__ src, short* __restrict__ hi, short* __restrict__ lo)
{
    const long i8 = (long)blockIdx.x * 256 + threadIdx.x;
    float4 x = ((const float4*)src)[i8 * 2];
    float4 y = ((const float4*)src)[i8 * 2 + 1];
    uint4 H, L; cvt8(x, y, H, L);
    ((uint4*)hi)[i8] = H; ((uint4*)lo)[i8] = L;
}

__global__ __launch_bounds__(256) void conv_gather_k(
    const float* __restrict__ emb, const int* __restrict__ input,
    short* __restrict__ hi, short* __restrict__ lo)
{
    const long i8 = (long)blockIdx.x * 256 + threadIdx.x;
    const int c8 = (int)(i8 & 127);
    const long row = i8 >> 7;
    const float* s = emb + (size_t)input[row] * 1024 + c8 * 8;
    float4 x = ((const float4*)s)[0];
    float4 y = ((const float4*)s)[1];
    uint4 H, L; cvt8(x, y, H, L);
    ((uint4*)hi)[i8] = H; ((uint4*)lo)[i8] = L;
}

// ============== big batched GEMM: 128x128 block tile (unchanged) ==============
template<int MODE, bool CONCAT>
__global__ __launch_bounds__(256, 2) void gemm_big(
    const short* __restrict__ A1h, const short* __restrict__ A1l,
    const short* __restrict__ A2h, const short* __restrict__ A2l,
    const short* __restrict__ Wh,  const short* __restrict__ Wl,
    int K, int nn,
    const float* __restrict__ bias,
    float* __restrict__ outf, short* __restrict__ outh, short* __restrict__ outl,
    int ldo)
{
    extern __shared__ short sm[];
    short* Asm = sm;
    short* Wsm = sm + 16384;
    const int tid = threadIdx.x;
    const int wv = tid >> 6, l = tid & 63;
    const int mq = wv >> 1, nq = wv & 1;
    const int gl = l >> 4, r16 = l & 15;

    const int cpx = gridDim.x >> 3;
    const int id = blockIdx.x;
    const int swz = (id & 7) * cpx + (id >> 3);
    const int bm = swz / nn, bn = swz % nn;
    const long Rbase = (long)bm * 128;
    const int  Cbase = bn * 128;

    const int lda = CONCAT ? (K >> 1) : K;
    const int NC = K >> 5;
    const int NCh = NC >> 1;

    const short *aP1[4], *aP2[4], *wP[4];
    int slda[4];
    #pragma unroll
    for (int j = 0; j < 4; ++j) {
        const int s = tid + j * 256;
        const int pl = s >> 9, sp = s & 511;
        const int row = ((sp >> 6) << 4) | (sp & 15);
        const int kg = (sp >> 4) & 3;
        slda[j] = s * 8;
        const short* a1 = pl ? A1l : A1h;
        aP1[j] = a1 + (Rbase + row) * (long)lda + kg * 8;
        if (CONCAT) {
            const short* a2 = pl ? A2l : A2h;
            aP2[j] = a2 + (Rbase + row) * (long)lda + kg * 8;
        } else aP2[j] = aP1[j];
        const short* wp = pl ? Wl : Wh;
        wP[j] = wp + ((long)Cbase + row) * (long)K + kg * 8;
    }

    f32x4 acc[4][4];
    #pragma unroll
    for (int i = 0; i < 4; ++i)
        #pragma unroll
        for (int j = 0; j < 4; ++j) acc[i][j] = (f32x4)0.f;

    short8 rA[4], rW[4];
    auto LOADC = [&](int c) {
        const bool p1 = !CONCAT || (c < NCh);
        const long ko = p1 ? (long)c * 32 : (long)c * 32 - (K >> 1);
        #pragma unroll
        for (int j = 0; j < 4; ++j) {
            rA[j] = *(const short8*)((p1 ? aP1[j] : aP2[j]) + ko);
            rW[j] = *(const short8*)(wP[j] + (long)c * 32);
        }
    };
    auto STORE = [&](int c) {
        const int b = (c & 1) << 13;
        #pragma unroll
        for (int j = 0; j < 4; ++j) {
            *(short8*)(Asm + b + slda[j]) = rA[j];
            *(short8*)(Wsm + b + slda[j]) = rW[j];
        }
    };

    LOADC(0); STORE(0); LOADC(1);
    __syncthreads();

    for (int c = 0; c < NC; ++c) {
        const int b = (c & 1) << 13;
        short8 ah[4], al[4], wh[4], wl[4];
        #pragma unroll
        for (int f = 0; f < 4; ++f) {
            const short* ab = Asm + b + ((mq * 4 + f) * 64 + l) * 8;
            ah[f] = *(const short8*)ab;
            al[f] = *(const short8*)(ab + 4096);
            const short* wb = Wsm + b + ((nq * 4 + f) * 64 + l) * 8;
            wh[f] = *(const short8*)wb;
            wl[f] = *(const short8*)(wb + 4096);
        }
        if (c + 1 < NC) STORE(c + 1);
        if (c + 2 < NC) LOADC(c + 2);
        #pragma unroll
        for (int mf = 0; mf < 4; ++mf)
            #pragma unroll
            for (int nf = 0; nf < 4; ++nf) {
                TRI(ah[mf], al[mf], wh[nf], wl[nf], acc[mf][nf]);
            }
        __syncthreads();
    }

    #pragma unroll
    for (int mf = 0; mf < 4; ++mf) {
        #pragma unroll
        for (int reg = 0; reg < 4; ++reg) {
            const long R = Rbase + mq * 64 + mf * 16 + gl * 4 + reg;
            #pragma unroll
            for (int nf = 0; nf < 4; ++nf) {
                const int col = Cbase + nq * 64 + nf * 16 + r16;
                const float v = acc[mf][nf][reg];
                if constexpr (MODE == 0) {
                    outf[R * (long)ldo + col] = v + bias[col];
                } else if constexpr (MODE == 1) {
                    const unsigned short hi = f2bf(v), lo = f2bf(v - bf2f(hi));
                    outh[R * (long)ldo + col] = (short)hi;
                    outl[R * (long)ldo + col] = (short)lo;
                } else {
                    outf[R * (long)ldo + col] = tanhf(v);
                }
            }
        }
    }
}

// ============== persistent recurrence kernel ==============
// 256 blocks (1/CU), 128 KB static LDS each, cooperative grid.sync pipeline.
// role 0 (blocks   0..63 ): h0 gate, W=whh0-hi resident (96KB), K=1024, DUO
// role 1 (blocks  64..191): gi1 partial = h0 @ w_ih1^T, TRI hi+lo, K=512 half
// role 2 (blocks 192..255): h1 gate, W=whh1-hi resident, K=1024, DUO
// phase p: role0 -> h0_p ; role1 -> gi1_{p-1} ; role2 -> h1_{p-2}
struct RecP {
    const short* hih; const short* hil;
    const float* h_in; const float* gi0;
    const short* whh0h; const short* wih1h; const short* wih1l; const short* whh1h;
    const float* b_hh0; const float* b_ih1; const float* b_hh1;
    float* h0f; float* h1f; float* gp;
    short* h0ah; short* h0al; short* h1ah; short* h1al;
};

__global__ __launch_bounds__(256, 1) void rec_k(RecP P, int ph0, int ph1)
{
    __shared__ short smr[65536];          // 96KB W-resident + 32KB A dbuf
    short* Wres = smr;                    // 6144 slots x 8 shorts
    short* Abuf = smr + 49152;            // 2 x 1024 slots x 8 shorts

    const int tid = threadIdx.x;
    const int wv = tid >> 6, l = tid & 63;
    const int gl = l >> 4, r16 = l & 15;
    const int id = blockIdx.x;

    int role, bj, kh = 0;
    if (id < 64)       { role = 0; bj = id; }
    else if (id < 192) { role = 1; bj = (id - 64) >> 1; kh = (id - 64) & 1; }
    else               { role = 2; bj = id - 192; }

    // ---- load resident W (once) ----
    if (role != 1) {
        const short* Wsrc = (role == 0) ? P.whh0h : P.whh1h;
        for (int i = 0; i < 24; ++i) {
            const int s = tid + i * 256;
            const int c = s / 192;
            const int rem = s - c * 192;
            const int p = rem >> 6, ll = rem & 63;
            const long grow = (long)p * HID + bj * 16 + (ll & 15);
            const int kg = c * 4 + (ll >> 4);
            *(short8*)(Wres + s * 8) = *(const short8*)(Wsrc + grow * HID + kg * 8);
        }
    } else {
        for (int i = 0; i < 24; ++i) {
            const int s = tid + i * 256;
            const int pl = (s >= 3072) ? 1 : 0;
            const int sp = s - pl * 3072;
            const int c = sp / 192;
            const int rem = sp - c * 192;
            const int p = rem >> 6, ll = rem & 63;
            const long grow = (long)p * HID + bj * 16 + (ll & 15);
            const int k = kh * 512 + (c * 4 + (ll >> 4)) * 8;
            const short* Wsrc = pl ? P.wih1l : P.wih1h;
            *(short8*)(Wres + s * 8) = *(const short8*)(Wsrc + grow * HID + k);
        }
    }
    __syncthreads();

    cg::grid_group grid = cg::this_grid();

    for (int ph = ph0; ph < ph1; ++ph) {
        const int s = (role == 0) ? ph : (role == 1) ? ph - 1 : ph - 2;
        const bool active = (s >= 0) && (s < T_STEPS);
        if (active) {
            const short *Ah, *Al;
            int NC, kOff;
            if (role == 0) {
                Ah = s ? P.h0ah + (size_t)(s - 1) * BH : P.hih;
                Al = s ? P.h0al + (size_t)(s - 1) * BH : P.hil;
                NC = 32; kOff = 0;
            } else if (role == 1) {
                Ah = P.h0ah + (size_t)s * BH;
                Al = P.h0al + (size_t)s * BH;
                NC = 16; kOff = kh * 512;
            } else {
                Ah = s ? P.h1ah + (size_t)(s - 1) * BH : P.hih + BH;
                Al = s ? P.h1al + (size_t)(s - 1) * BH : P.hil + BH;
                NC = 32; kOff = 0;
            }

            const short* aP[4]; int sl[4];
            #pragma unroll
            for (int i = 0; i < 4; ++i) {
                const int s4 = tid + i * 256;
                const int pl = s4 >> 9, sp = s4 & 511;
                const int rt = sp >> 6, ll = sp & 63;
                const int row = rt * 16 + (ll & 15);
                const int kg = ll >> 4;
                aP[i] = (pl ? Al : Ah) + (size_t)row * HID + kOff + kg * 8;
                sl[i] = s4 * 8;
            }
            short8 rg[4];
            auto LOADC = [&](int c) {
                #pragma unroll
                for (int i = 0; i < 4; ++i) rg[i] = *(const short8*)(aP[i] + c * 32);
            };
            auto STORE = [&](int c) {
                short* base = Abuf + (c & 1) * 8192;
                #pragma unroll
                for (int i = 0; i < 4; ++i) *(short8*)(base + sl[i]) = rg[i];
            };

            f32x4 acc[2][3];
            #pragma unroll
            for (int a = 0; a < 2; ++a)
                #pragma unroll
                for (int b = 0; b < 3; ++b) acc[a][b] = (f32x4)0.f;

            LOADC(0); STORE(0); LOADC(1);
            __syncthreads();
            for (int c = 0; c < NC; ++c) {
                const short* ab = Abuf + (c & 1) * 8192;
                short8 fa[2][2];
                #pragma unroll
                for (int mf = 0; mf < 2; ++mf) {
                    const int rt = 2 * wv + mf;
                    fa[mf][0] = *(const short8*)(ab + (rt * 64 + l) * 8);
                    fa[mf][1] = *(const short8*)(ab + (512 + rt * 64 + l) * 8);
                }
                short8 fw[3], fl[3];
                #pragma unroll
                for (int p = 0; p < 3; ++p) {
                    fw[p] = *(const short8*)(Wres + ((c * 3 + p) * 64 + l) * 8);
                    if (role == 1)
                        fl[p] = *(const short8*)(Wres + (3072 + (c * 3 + p) * 64 + l) * 8);
                }
                if (c + 1 < NC) STORE(c + 1);
                if (c + 2 < NC) LOADC(c + 2);
                #pragma unroll
                for (int mf = 0; mf < 2; ++mf)
                    #pragma unroll
                    for (int p = 0; p < 3; ++p) {
                        if (role == 1) { MF(fa[mf][0], fl[p], acc[mf][p]); }
                        MF(fa[mf][1], fw[p], acc[mf][p]);
                        MF(fa[mf][0], fw[p], acc[mf][p]);
                    }
                __syncthreads();
            }

            const int jc = bj * 16 + r16;
            if (role == 0) {
                const float* gi = P.gi0 + (size_t)s * BATCH * H3;
                const float* hp = s ? P.h0f + (size_t)((s - 1) & 1) * BH : P.h_in;
                float* ho = P.h0f + (size_t)(s & 1) * BH;
                short* phi = P.h0ah + (size_t)s * BH;
                short* plo = P.h0al + (size_t)s * BH;
                #pragma unroll
                for (int mf = 0; mf < 2; ++mf)
                    #pragma unroll
                    for (int reg = 0; reg < 4; ++reg) {
                        const long R = wv * 32 + mf * 16 + gl * 4 + reg;
                        const float* orow = gi + R * H3;
                        const float rr = sigf(orow[jc] + acc[mf][0][reg] + P.b_hh0[jc]);
                        const float zz = sigf(orow[HID + jc] + acc[mf][1][reg] + P.b_hh0[HID + jc]);
                        const float nn = tanhf(orow[2 * HID + jc] +
                                               rr * (acc[mf][2][reg] + P.b_hh0[2 * HID + jc]));
                        const float h = (1.f - zz) * nn + zz * hp[R * HID + jc];
                        ho[R * HID + jc] = h;
                        const unsigned short hb = f2bf(h), lb = f2bf(h - bf2f(hb));
                        phi[R * HID + jc] = (short)hb; plo[R * HID + jc] = (short)lb;
                    }
            } else if (role == 1) {
                float* g = P.gp + (size_t)((s & 1) * 2 + kh) * BATCH * H3;
                #pragma unroll
                for (int mf = 0; mf < 2; ++mf)
                    #pragma unroll
                    for (int reg = 0; reg < 4; ++reg) {
                        const long R = wv * 32 + mf * 16 + gl * 4 + reg;
                        #pragma unroll
                        for (int p = 0; p < 3; ++p)
                            g[R * H3 + p * HID + jc] = acc[mf][p][reg];
                    }
            } else {
                const float* g0 = P.gp + (size_t)((s & 1) * 2 + 0) * BATCH * H3;
                const float* g1 = P.gp + (size_t)((s & 1) * 2 + 1) * BATCH * H3;
                const float* hp = s ? P.h1f + (size_t)((s - 1) & 1) * BH : P.h_in + BH;
                float* ho = P.h1f + (size_t)(s & 1) * BH;
                short* phi = P.h1ah + (size_t)s * BH;
                short* plo = P.h1al + (size_t)s * BH;
                #pragma unroll
                for (int mf = 0; mf < 2; ++mf)
                    #pragma unroll
                    for (int reg = 0; reg < 4; ++reg) {
                        const long R = wv * 32 + mf * 16 + gl * 4 + reg;
                        const float ir = g0[R * H3 + jc] + g1[R * H3 + jc] + P.b_ih1[jc];
                        const float iz = g0[R * H3 + HID + jc] + g1[R * H3 + HID + jc] + P.b_ih1[HID + jc];
                        const float in_ = g0[R * H3 + 2 * HID + jc] + g1[R * H3 + 2 * HID + jc] + P.b_ih1[2 * HID + jc];
                        const float rr = sigf(ir + acc[mf][0][reg] + P.b_hh1[jc]);
                        const float zz = sigf(iz + acc[mf][1][reg] + P.b_hh1[HID + jc]);
                        const float nn = tanhf(in_ + rr * (acc[mf][2][reg] + P.b_hh1[2 * HID + jc]));
                        const float h = (1.f - zz) * nn + zz * hp[R * HID + jc];
                        ho[R * HID + jc] = h;
                        const unsigned short hb = f2bf(h), lb = f2bf(h - bf2f(hb));
                        phi[R * HID + jc] = (short)hb; plo[R * HID + jc] = (short)lb;
                    }
            }
        }
        if (ph + 1 < ph1) {           // grid barrier only in cooperative mode
            __threadfence();
            grid.sync();
        }
    }
}

// ============== batched attention scores + softmax (per b) ==============
__global__ __launch_bounds__(256) void scores_k(
    const short* __restrict__ Qh, const short* __restrict__ Ql,
    const short* __restrict__ Hh, const short* __restrict__ Hl,
    float* __restrict__ Pall)
{
    extern __shared__ short sm[];
    short* Asm = sm;
    short* Wsm = sm + 8192;
    const int b = blockIdx.x, tid = threadIdx.x;
    const int wv = tid >> 6, l = tid & 63;
    const int gl = l >> 4, cc = l & 15;

    const int arow = ((tid >> 6) & 3) * 16 + (tid & 15);
    const int ag   = (tid >> 4) & 3;
    const short* qhp = Qh + ((long)arow * BATCH + b) * HID + ag * 8;
    const short* qlp = Ql + ((long)arow * BATCH + b) * HID + ag * 8;
    const int aLds = tid * 8;

    const short *whp[2], *wlp[2]; int wLds[2];
    #pragma unroll
    for (int i = 0; i < 2; ++i) {
        const int s = tid + i * 256;
        const int srow = ((s >> 6) & 7) * 16 + (s & 15);
        const int sg   = (s >> 4) & 3;
        whp[i] = Hh + ((long)srow * BATCH + b) * HID + sg * 8;
        wlp[i] = Hl + ((long)srow * BATCH + b) * HID + sg * 8;
        wLds[i] = s * 8;
    }

    f32x4 acc[8];
    #pragma unroll
    for (int i = 0; i < 8; ++i) acc[i] = (f32x4)0.f;

    short8 rAh, rAl, rWh[2], rWl[2];
    auto LOADC = [&](int c) {
        rAh = *(const short8*)(qhp + c * 32);
        rAl = *(const short8*)(qlp + c * 32);
        #pragma unroll
        for (int i = 0; i < 2; ++i) {
            rWh[i] = *(const short8*)(whp[i] + c * 32);
            rWl[i] = *(const short8*)(wlp[i] + c * 32);
        }
    };
    auto STORE = [&](int c) {
        const int bb = c & 1;
        *(short8*)(Asm + bb * 4096 + aLds) = rAh;
        *(short8*)(Asm + bb * 4096 + 2048 + aLds) = rAl;
        #pragma unroll
        for (int i = 0; i < 2; ++i) {
            *(short8*)(Wsm + bb * 8192 + wLds[i]) = rWh[i];
            *(short8*)(Wsm + bb * 8192 + 4096 + wLds[i]) = rWl[i];
        }
    };

    LOADC(0); STORE(0); LOADC(1);
    __syncthreads();
    for (int c = 0; c < 32; ++c) {
        const int bb = c & 1;
        const short* abp = Asm + bb * 4096 + (wv * 64 + l) * 8;
        short8 ah = *(const short8*)abp;
        short8 al = *(const short8*)(abp + 2048);
        if (c + 1 < 32) STORE(c + 1);
        if (c + 2 < 32) LOADC(c + 2);
        #pragma unroll
        for (int jt = 0; jt < 8; ++jt) {
            const short* wbp = Wsm + bb * 8192 + (jt * 64 + l) * 8;
            short8 wh = *(const short8*)wbp;
            short8 wl = *(const short8*)(wbp + 4096);
            TRI(ah, al, wh, wl, acc[jt]);
        }
        __syncthreads();
    }

    #pragma unroll
    for (int reg = 0; reg < 4; ++reg) {
        float m = acc[0][reg];
        #pragma unroll
        for (int jt = 1; jt < 8; ++jt) m = fmaxf(m, acc[jt][reg]);
        #pragma unroll
        for (int off = 1; off < 16; off <<= 1) m = fmaxf(m, __shfl_xor(m, off));
        float e[8], ssum = 0.f;
        #pragma unroll
        for (int jt = 0; jt < 8; ++jt) { e[jt] = __expf(acc[jt][reg] - m); ssum += e[jt]; }
        #pragma unroll
        for (int off = 1; off < 16; off <<= 1) ssum += __shfl_xor(ssum, off);
        const float inv = 1.f / ssum;
        const int t = wv * 16 + gl * 4 + reg;
        #pragma unroll
        for (int jt = 0; jt < 8; ++jt)
            Pall[((long)t * BATCH + b) * SLEN + jt * 16 + cc] = e[jt] * inv;
    }
}

__global__ __launch_bounds__(256) void ctx_k(
    const float* __restrict__ Pall, const float* __restrict__ H,
    short* __restrict__ Ch, short* __restrict__ Cl)
{
    __shared__ float Ps[T_STEPS * SLEN];
    const int b = blockIdx.x, ht = blockIdx.y, tid = threadIdx.x;
    for (int i = 0; i < 32; ++i) {
        const int idx = i * 256 + tid;
        const int t = idx >> 7, s = idx & 127;
        Ps[idx] = Pall[((long)t * BATCH + b) * SLEN + s];
    }
    __syncthreads();
    const int col = ht * 256 + tid;
    for (int tg = 0; tg < 4; ++tg) {
        float a[16];
        #pragma unroll
        for (int j = 0; j < 16; ++j) a[j] = 0.f;
        for (int s = 0; s < SLEN; ++s) {
            const float hv = H[((long)s * BATCH + b) * HID + col];
            #pragma unroll
            for (int j = 0; j < 16; ++j)
                a[j] = fmaf(Ps[(tg * 16 + j) * SLEN + s], hv, a[j]);
        }
        #pragma unroll
        for (int j = 0; j < 16; ++j) {
            const long row = (long)(tg * 16 + j) * BATCH + b;
            const unsigned short hi = f2bf(a[j]);
            const unsigned short lo = f2bf(a[j] - bf2f(hi));
            Ch[row * HID + col] = (short)hi;
            Cl[row * HID + col] = (short)lo;
        }
    }
}

// =========================== launch ===========================
extern "C" void kernel_launch(void* const* d_in, const int* in_sizes, int n_in,
                              void* d_out, int out_size, void* d_ws, size_t ws_size,
                              hipStream_t stream)
{
    const int*   input = (const int*)  d_in[0];
    const float* h_in  = (const float*)d_in[1];
    const float* Hbuf  = (const float*)d_in[2];
    const float* emb   = (const float*)d_in[3];
    const float* w_ih  = (const float*)d_in[4];
    const float* w_hh  = (const float*)d_in[5];
    const float* b_ih  = (const float*)d_in[6];
    const float* b_hh  = (const float*)d_in[7];
    const float* L1    = (const float*)d_in[8];
    const float* L2    = (const float*)d_in[9];

    float* out = (float*)d_out;

    char* basep = (char*)d_ws;
    size_t off = 0;
    auto alloc = [&](size_t bytes) -> char* {
        off = (off + 255) & ~(size_t)255;
        char* p = basep + off; off += bytes; return p;
    };
    short* wihH = (short*)alloc(2L*3072*1024*2); short* wihL = (short*)alloc(2L*3072*1024*2);
    short* whhH = (short*)alloc(2L*3072*1024*2); short* whhL = (short*)alloc(2L*3072*1024*2);
    short* l1h  = (short*)alloc(1024L*1024*2);   short* l1l  = (short*)alloc(1024L*1024*2);
    short* l2h  = (short*)alloc(1024L*2048*2);   short* l2l  = (short*)alloc(1024L*2048*2);
    short* Hh   = (short*)alloc(16777216L*2);    short* Hl   = (short*)alloc(16777216L*2);
    short* hih  = (short*)alloc(262144L*2);      short* hil  = (short*)alloc(262144L*2);
    short* h0ah = (short*)alloc(8388608L*2);     short* h0al = (short*)alloc(8388608L*2);
    short* h1ah = (short*)alloc(8388608L*2);     short* h1al = (short*)alloc(8388608L*2);
    short* eqh  = (short*)alloc(8388608L*2);     short* eql  = (short*)alloc(8388608L*2);
    float* gi0  = (float*)alloc(25165824L*4);
    float* h0f  = (float*)alloc(524288L*4);
    float* h1f  = (float*)alloc(524288L*4);
    float* Pall = (float*)alloc(1048576L*4);
    float* gp   = (float*)alloc(4L*BATCH*H3*4);
    short* ctxh = (short*)gi0;                   // gi0 dead after recurrence
    short* ctxl = ctxh + 8388608L;

    const short* wih0h = wihH;                const short* wih0l = wihL;
    const short* wih1h = wihH + 3145728L;     const short* wih1l = wihL + 3145728L;
    const short* whh0h = whhH;
    const short* whh1h = whhH + 3145728L;

    const dim3 blk(256);
    const size_t SMB = 32768 * sizeof(short);   // 64 KB for gemm_big

    // ---- phase 0: plane conversions ----
    conv_planes_k<<<3072, blk, 0, stream>>>(w_ih, wihH, wihL);
    conv_planes_k<<<3072, blk, 0, stream>>>(w_hh, whhH, whhL);
    conv_planes_k<<<512,  blk, 0, stream>>>(L1, l1h, l1l);
    conv_planes_k<<<1024, blk, 0, stream>>>(L2, l2h, l2l);
    conv_planes_k<<<8192, blk, 0, stream>>>(Hbuf, Hh, Hl);
    conv_planes_k<<<128,  blk, 0, stream>>>(h_in, hih, hil);
    conv_gather_k<<<4096, blk, 0, stream>>>(emb, input, eqh, eql);

    // gi0_all = E @ w_ih0^T + b_ih0   (8192 x 3072 x 1024)
    gemm_big<0, false><<<dim3(1536), blk, SMB, stream>>>(
        eqh, eql, nullptr, nullptr, wih0h, wih0l, 1024, 24,
        b_ih, gi0, nullptr, nullptr, H3);

    // ---- persistent recurrence (cooperative; fallback = 66 regular launches) ----
    RecP rp;
    rp.hih = hih; rp.hil = hil; rp.h_in = h_in; rp.gi0 = gi0;
    rp.whh0h = whh0h; rp.wih1h = wih1h; rp.wih1l = wih1l; rp.whh1h = whh1h;
    rp.b_hh0 = b_hh; rp.b_ih1 = b_ih + H3; rp.b_hh1 = b_hh + H3;
    rp.h0f = h0f; rp.h1f = h1f; rp.gp = gp;
    rp.h0ah = h0ah; rp.h0al = h0al; rp.h1ah = h1ah; rp.h1al = h1al;
    int p0 = 0, p1 = T_STEPS + 2;
    void* kargs[] = { (void*)&rp, (void*)&p0, (void*)&p1 };
    hipError_t ce = hipLaunchCooperativeKernel((void*)rec_k, dim3(256), dim3(256),
                                               kargs, 0, stream);
    if (ce != hipSuccess) {
        for (int ph = 0; ph < T_STEPS + 2; ++ph)
            rec_k<<<dim3(256), blk, 0, stream>>>(rp, ph, ph + 1);
    }

    // ---- batched attention + output ----
    gemm_big<1, false><<<dim3(512), blk, SMB, stream>>>(
        h1ah, h1al, nullptr, nullptr, l1h, l1l, 1024, 8,
        nullptr, nullptr, eqh, eql, HID);
    scores_k<<<dim3(BATCH), blk, 49152, stream>>>(eqh, eql, Hh, Hl, Pall);
    ctx_k<<<dim3(BATCH, 4), blk, 0, stream>>>(Pall, Hbuf, ctxh, ctxl);
    gemm_big<2, true><<<dim3(512), blk, SMB, stream>>>(
        ctxh, ctxl, h1ah, h1al, l2h, l2l, 2048, 8,
        nullptr, out, nullptr, nullptr, HID);

    hipMemcpyAsync(out + (long)T_STEPS * BH, h0f + BH, (size_t)BH * 4,
                   hipMemcpyDeviceToDevice, stream);
    hipMemcpyAsync(out + (long)T_STEPS * BH + BH, h1f + BH, (size_t)BH * 4,
                   hipMemcpyDeviceToDevice, stream);
}

// Round 8
// 2329.421 us; speedup vs baseline: 2.4384x; 2.4384x over previous
//
#include <hip/hip_runtime.h>

#define T_STEPS 64
#define BATCH   128
#define HID     1024
#define H3      3072
#define EMBD    1024
#define SLEN    128
#define BH      (BATCH * HID)

typedef __attribute__((ext_vector_type(8))) short short8;
typedef __attribute__((ext_vector_type(4))) float f32x4;

__device__ __forceinline__ unsigned short f2bf(float x) {
    unsigned int u = __float_as_uint(x);
    unsigned int r = (u + 0x7fffu + ((u >> 16) & 1u)) >> 16;
    return (unsigned short)r;
}
__device__ __forceinline__ float bf2f(unsigned short h) {
    return __uint_as_float(((unsigned int)h) << 16);
}
__device__ __forceinline__ unsigned int pk(unsigned short a, unsigned short b) {
    return (unsigned int)a | ((unsigned int)b << 16);
}
__device__ __forceinline__ void cvt8(const float4& x, const float4& y,
                                     uint4& H, uint4& L) {
    unsigned short h0 = f2bf(x.x), h1 = f2bf(x.y), h2 = f2bf(x.z), h3 = f2bf(x.w);
    unsigned short h4 = f2bf(y.x), h5 = f2bf(y.y), h6 = f2bf(y.z), h7 = f2bf(y.w);
    unsigned short l0 = f2bf(x.x - bf2f(h0)), l1 = f2bf(x.y - bf2f(h1));
    unsigned short l2 = f2bf(x.z - bf2f(h2)), l3 = f2bf(x.w - bf2f(h3));
    unsigned short l4 = f2bf(y.x - bf2f(h4)), l5 = f2bf(y.y - bf2f(h5));
    unsigned short l6 = f2bf(y.z - bf2f(h6)), l7 = f2bf(y.w - bf2f(h7));
    H = make_uint4(pk(h0,h1), pk(h2,h3), pk(h4,h5), pk(h6,h7));
    L = make_uint4(pk(l0,l1), pk(l2,l3), pk(l4,l5), pk(l6,l7));
}
__device__ __forceinline__ float sigf(float x) {
    return 1.f / (1.f + __expf(-x));
}

#define MF(A, B, ACC) ACC = __builtin_amdgcn_mfma_f32_16x16x32_bf16(A, B, ACC, 0, 0, 0)
#define TRI(AH, AL, WH, WL, ACC)  MF(AH, WL, ACC); MF(AL, WH, ACC); MF(AH, WH, ACC);

// ============== plane-conversion kernels (run once per call) ==============
__global__ __launch_bounds__(256) void conv_planes_k(
    const float* __restrict__ src, short* __restrict__ hi, short* __restrict__ lo)
{
    const long i8 = (long)blockIdx.x * 256 + threadIdx.x;
    float4 x = ((const float4*)src)[i8 * 2];
    float4 y = ((const float4*)src)[i8 * 2 + 1];
    uint4 H, L; cvt8(x, y, H, L);
    ((uint4*)hi)[i8] = H; ((uint4*)lo)[i8] = L;
}

__global__ __launch_bounds__(256) void conv_gather_k(
    const float* __restrict__ emb, const int* __restrict__ input,
    short* __restrict__ hi, short* __restrict__ lo)
{
    const long i8 = (long)blockIdx.x * 256 + threadIdx.x;
    const int c8 = (int)(i8 & 127);
    const long row = i8 >> 7;
    const float* s = emb + (size_t)input[row] * 1024 + c8 * 8;
    float4 x = ((const float4*)s)[0];
    float4 y = ((const float4*)s)[1];
    uint4 H, L; cvt8(x, y, H, L);
    ((uint4*)hi)[i8] = H; ((uint4*)lo)[i8] = L;
}

// ============== big batched GEMM: 128x128 block tile ==============
// WLO: skip the Ah*Wl term (drop W lo plane from compute) — 2 MFMA / tile.
template<int MODE, bool CONCAT, bool WLO>
__global__ __launch_bounds__(256, 2) void gemm_big(
    const short* __restrict__ A1h, const short* __restrict__ A1l,
    const short* __restrict__ A2h, const short* __restrict__ A2l,
    const short* __restrict__ Wh,  const short* __restrict__ Wl,
    int K, int nn,
    const float* __restrict__ bias,
    float* __restrict__ outf, short* __restrict__ outh, short* __restrict__ outl,
    int ldo)
{
    extern __shared__ short sm[];
    short* Asm = sm;
    short* Wsm = sm + 16384;
    const int tid = threadIdx.x;
    const int wv = tid >> 6, l = tid & 63;
    const int mq = wv >> 1, nq = wv & 1;
    const int gl = l >> 4, r16 = l & 15;

    const int cpx = gridDim.x >> 3;
    const int id = blockIdx.x;
    const int swz = (id & 7) * cpx + (id >> 3);
    const int bm = swz / nn, bn = swz % nn;
    const long Rbase = (long)bm * 128;
    const int  Cbase = bn * 128;

    const int lda = CONCAT ? (K >> 1) : K;
    const int NC = K >> 5;
    const int NCh = NC >> 1;

    const short *aP1[4], *aP2[4], *wP[4];
    int slda[4];
    #pragma unroll
    for (int j = 0; j < 4; ++j) {
        const int s = tid + j * 256;
        const int pl = s >> 9, sp = s & 511;
        const int row = ((sp >> 6) << 4) | (sp & 15);
        const int kg = (sp >> 4) & 3;
        slda[j] = s * 8;
        const short* a1 = pl ? A1l : A1h;
        aP1[j] = a1 + (Rbase + row) * (long)lda + kg * 8;
        if (CONCAT) {
            const short* a2 = pl ? A2l : A2h;
            aP2[j] = a2 + (Rbase + row) * (long)lda + kg * 8;
        } else aP2[j] = aP1[j];
        const short* wp = pl ? Wl : Wh;
        wP[j] = wp + ((long)Cbase + row) * (long)K + kg * 8;
    }

    f32x4 acc[4][4];
    #pragma unroll
    for (int i = 0; i < 4; ++i)
        #pragma unroll
        for (int j = 0; j < 4; ++j) acc[i][j] = (f32x4)0.f;

    short8 rA[4], rW[4];
    auto LOADC = [&](int c) {
        const bool p1 = !CONCAT || (c < NCh);
        const long ko = p1 ? (long)c * 32 : (long)c * 32 - (K >> 1);
        #pragma unroll
        for (int j = 0; j < 4; ++j) {
            rA[j] = *(const short8*)((p1 ? aP1[j] : aP2[j]) + ko);
            rW[j] = *(const short8*)(wP[j] + (long)c * 32);
        }
    };
    auto STORE = [&](int c) {
        const int b = (c & 1) << 13;
        #pragma unroll
        for (int j = 0; j < 4; ++j) {
            *(short8*)(Asm + b + slda[j]) = rA[j];
            *(short8*)(Wsm + b + slda[j]) = rW[j];
        }
    };

    LOADC(0); STORE(0); LOADC(1);
    __syncthreads();

    for (int c = 0; c < NC; ++c) {
        const int b = (c & 1) << 13;
        short8 ah[4], al[4], wh[4], wl[4];
        #pragma unroll
        for (int f = 0; f < 4; ++f) {
            const short* ab = Asm + b + ((mq * 4 + f) * 64 + l) * 8;
            ah[f] = *(const short8*)ab;
            al[f] = *(const short8*)(ab + 4096);
            const short* wb = Wsm + b + ((nq * 4 + f) * 64 + l) * 8;
            wh[f] = *(const short8*)wb;
            if (!WLO) wl[f] = *(const short8*)(wb + 4096);
        }
        if (c + 1 < NC) STORE(c + 1);
        if (c + 2 < NC) LOADC(c + 2);
        #pragma unroll
        for (int mf = 0; mf < 4; ++mf)
            #pragma unroll
            for (int nf = 0; nf < 4; ++nf) {
                if constexpr (WLO) {
                    MF(al[mf], wh[nf], acc[mf][nf]);
                    MF(ah[mf], wh[nf], acc[mf][nf]);
                } else {
                    TRI(ah[mf], al[mf], wh[nf], wl[nf], acc[mf][nf]);
                }
            }
        __syncthreads();
    }

    #pragma unroll
    for (int mf = 0; mf < 4; ++mf) {
        #pragma unroll
        for (int reg = 0; reg < 4; ++reg) {
            const long R = Rbase + mq * 64 + mf * 16 + gl * 4 + reg;
            #pragma unroll
            for (int nf = 0; nf < 4; ++nf) {
                const int col = Cbase + nq * 64 + nf * 16 + r16;
                const float v = acc[mf][nf][reg];
                if constexpr (MODE == 0) {
                    outf[R * (long)ldo + col] = v + bias[col];
                } else if constexpr (MODE == 1) {
                    const unsigned short hi = f2bf(v), lo = f2bf(v - bf2f(hi));
                    outh[R * (long)ldo + col] = (short)hi;
                    outl[R * (long)ldo + col] = (short)lo;
                } else {
                    outf[R * (long)ldo + col] = tanhf(v);
                }
            }
        }
    }
}

// ============== split-K step GEMM core (2 blocks/CU, 8 waves/CU) ==============
// Block: BM=32 rows (bm 0..3), 16 cols x 3 gates (bj 0..63). 4 waves:
// wave = (mt = wv&1 -> 16-row tile, kp = wv>>1 -> K-half). LDS cross-pair
// reduction, then gate epilogue on waves kp=0.
// MODE 2: layer-0 gate (K=1024, DUO); gi = precomputed i-side (f32, H3).
// MODE 3: layer-1 concat (K=2048): part0 = w_ih1 side TRI (A=h0[t]);
//         part1 = w_hh1 side DUO (A=h1[t-1]); n-gate halves kept separate.
template<int MODE>
__device__ __forceinline__ void gru_sk(
    short* __restrict__ sm,
    const short* __restrict__ A1h, const short* __restrict__ A1l,
    const short* __restrict__ A2h, const short* __restrict__ A2l,
    const short* __restrict__ W1h, const short* __restrict__ W1l,
    const short* __restrict__ W2h,
    const float* __restrict__ bias1, const float* __restrict__ bias2,
    const float* __restrict__ gi,
    const float* __restrict__ hprev,
    float* __restrict__ outf, short* __restrict__ outh, short* __restrict__ outl)
{
    short* Wb = sm + 16384;       // A: 2buf x 8192 shorts; W: 2buf x 9216
    const int tid = threadIdx.x;
    const int wv = tid >> 6, l = tid & 63;
    const int mt = wv & 1, kp = wv >> 1;
    const int gl = l >> 4, r16 = l & 15;
    const int bm = blockIdx.x, bj = blockIdx.y;
    constexpr int NC = (MODE == 2) ? 8 : 16;

    // ---- A staging: 1024 slots (part, plane, kc, mtile, kg, row), 4/thread ----
    const short* aP[4]; int aL[4];
    #pragma unroll
    for (int i = 0; i < 4; ++i) {
        const int s = tid + i * 256;
        const int part = s >> 9, pl = (s >> 8) & 1, sl = s & 255;
        const int kc = sl >> 7, m = (sl >> 6) & 1;
        const int g = (kc << 2) | ((sl >> 4) & 3);
        const int row = m * 16 + (sl & 15);
        const short* src = part ? (pl ? A2l : A2h) : (pl ? A1l : A1h);
        aP[i] = src + (size_t)(bm * 32 + row) * HID + g * 8;
        aL[i] = s * 8;
    }
    // ---- W staging: regions {p0-hi, p0-lo, p1-hi} x 384 slots ----
    const short* wP[5]; int wL[5]; bool wV[5];
    #pragma unroll
    for (int i = 0; i < 5; ++i) {
        const int s = tid + i * 256;
        bool v = (s < 1152);
        const int reg3 = s / 384;
        if (MODE == 2 && reg3 == 1) v = false;
        const int sub = s - reg3 * 384;
        const int p = sub >> 7, kc = (sub >> 6) & 1;
        const int g = (kc << 2) | ((sub >> 4) & 3);
        const int jr = sub & 15;
        const short* src = (reg3 == 0) ? W1h : (reg3 == 1) ? W1l : W2h;
        wP[i] = v ? src + (size_t)(p * HID + bj * 16 + jr) * HID + g * 8 : A1h;
        wL[i] = s * 8;
        wV[i] = v;
    }

    f32x4 acc[3];
    acc[0] = (f32x4)0.f; acc[1] = (f32x4)0.f; acc[2] = (f32x4)0.f;

    short8 ra[4], rw[5];
    auto LOADC = [&](int c) {
        #pragma unroll
        for (int i = 0; i < 4; ++i) ra[i] = *(const short8*)(aP[i] + c * 64);
        #pragma unroll
        for (int i = 0; i < 5; ++i)
            if (wV[i]) rw[i] = *(const short8*)(wP[i] + c * 64);
    };
    auto STORE = [&](int c) {
        short* ab = sm + (c & 1) * 8192;
        short* wb = Wb + (c & 1) * 9216;
        #pragma unroll
        for (int i = 0; i < 4; ++i) *(short8*)(ab + aL[i]) = ra[i];
        #pragma unroll
        for (int i = 0; i < 5; ++i)
            if (wV[i]) *(short8*)(wb + wL[i]) = rw[i];
    };

    LOADC(0); STORE(0); LOADC(1);
    __syncthreads();

    for (int c = 0; c < NC; ++c) {
        const short* ab = sm + (c & 1) * 8192 + kp * 4096;
        const short* wb = Wb + (c & 1) * 9216 + kp * 6144;
        short8 fh[2], fl[2], fwh[3][2], fwl[3][2];
        #pragma unroll
        for (int kc = 0; kc < 2; ++kc) {
            const int fo = ((kc * 2 + mt) * 64 + l) * 8;
            fh[kc] = *(const short8*)(ab + fo);
            fl[kc] = *(const short8*)(ab + 2048 + fo);
        }
        #pragma unroll
        for (int p = 0; p < 3; ++p)
            #pragma unroll
            for (int kc = 0; kc < 2; ++kc) {
                const int wo = ((p * 2 + kc) * 64 + l) * 8;
                fwh[p][kc] = *(const short8*)(wb + wo);
                if (MODE == 3 && kp == 0)
                    fwl[p][kc] = *(const short8*)(wb + 3072 + wo);
            }
        if (c + 1 < NC) STORE(c + 1);
        if (c + 2 < NC) LOADC(c + 2);
        #pragma unroll
        for (int p = 0; p < 3; ++p)
            #pragma unroll
            for (int kc = 0; kc < 2; ++kc) {
                if (MODE == 3 && kp == 0) { MF(fh[kc], fwl[p][kc], acc[p]); }
                MF(fl[kc], fwh[p][kc], acc[p]);
                MF(fh[kc], fwh[p][kc], acc[p]);
            }
        __syncthreads();
    }

    // ---- cross-pair reduction (reuse A region) ----
    float* red = (float*)sm;
    if (kp == 1) {
        #pragma unroll
        for (int p = 0; p < 3; ++p)
            *(f32x4*)(red + ((mt * 3 + p) * 64 + l) * 4) = acc[p];
    }
    __syncthreads();
    if (kp == 1) return;

    f32x4 o0 = *(const f32x4*)(red + ((mt * 3 + 0) * 64 + l) * 4);
    f32x4 o1 = *(const f32x4*)(red + ((mt * 3 + 1) * 64 + l) * 4);
    f32x4 o2 = *(const f32x4*)(red + ((mt * 3 + 2) * 64 + l) * 4);

    const int jc = bj * 16 + r16;
    #pragma unroll
    for (int reg = 0; reg < 4; ++reg) {
        const long R = (long)bm * 32 + mt * 16 + gl * 4 + reg;
        float h;
        if constexpr (MODE == 2) {
            const float* orow = gi + R * H3;
            const float rr = sigf(orow[jc] + acc[0][reg] + o0[reg] + bias1[jc]);
            const float zz = sigf(orow[HID + jc] + acc[1][reg] + o1[reg] + bias1[HID + jc]);
            const float nn = tanhf(orow[2 * HID + jc] +
                                   rr * (acc[2][reg] + o2[reg] + bias1[2 * HID + jc]));
            h = (1.f - zz) * nn + zz * hprev[R * HID + jc];
        } else {
            const float rr = sigf(acc[0][reg] + o0[reg] + bias1[jc] + bias2[jc]);
            const float zz = sigf(acc[1][reg] + o1[reg] + bias1[HID + jc] + bias2[HID + jc]);
            const float nn = tanhf(acc[2][reg] + bias1[2 * HID + jc] +
                                   rr * (o2[reg] + bias2[2 * HID + jc]));
            h = (1.f - zz) * nn + zz * hprev[R * HID + jc];
        }
        outf[R * HID + jc] = h;
        const unsigned short hb = f2bf(h), lb = f2bf(h - bf2f(hb));
        outh[R * HID + jc] = (short)hb;
        outl[R * HID + jc] = (short)lb;
    }
}

struct StepP {
    const short* hih; const short* hil;
    const float* h_in; const float* gi0;
    const short* whh0h;
    const short* wih1h; const short* wih1l; const short* whh1h;
    const float* b_hh0; const float* b_ih1; const float* b_hh1;
    float* h0f; float* h1f;
    short* h0ah; short* h0al; short* h1ah; short* h1al;
};

__global__ __launch_bounds__(256) void step_k(int t, StepP P)
{
    __shared__ short sm[34816];   // 69632 B -> 2 blocks/CU
    if (blockIdx.z == 0) {
        if (t >= T_STEPS) return;
        const short* a1h = t ? P.h0ah + (size_t)(t - 1) * BH : P.hih;
        const short* a1l = t ? P.h0al + (size_t)(t - 1) * BH : P.hil;
        gru_sk<2>(sm, a1h, a1l, a1h + 512, a1l + 512,
                  P.whh0h, nullptr, P.whh0h + 512,
                  P.b_hh0, nullptr,
                  P.gi0 + (size_t)t * BATCH * H3,
                  t ? P.h0f + (size_t)((t - 1) & 1) * BH : P.h_in,
                  P.h0f + (size_t)(t & 1) * BH,
                  P.h0ah + (size_t)t * BH, P.h0al + (size_t)t * BH);
    } else {
        if (t < 1) return;
        const int s = t - 1;
        const short* a2h = s ? P.h1ah + (size_t)(s - 1) * BH : P.hih + BH;
        const short* a2l = s ? P.h1al + (size_t)(s - 1) * BH : P.hil + BH;
        gru_sk<3>(sm, P.h0ah + (size_t)s * BH, P.h0al + (size_t)s * BH, a2h, a2l,
                  P.wih1h, P.wih1l, P.whh1h,
                  P.b_ih1, P.b_hh1,
                  nullptr,
                  s ? P.h1f + (size_t)((s - 1) & 1) * BH : P.h_in + BH,
                  P.h1f + (size_t)(s & 1) * BH,
                  P.h1ah + (size_t)s * BH, P.h1al + (size_t)s * BH);
    }
}

// ============== batched attention scores + softmax (per b) ==============
__global__ __launch_bounds__(256) void scores_k(
    const short* __restrict__ Qh, const short* __restrict__ Ql,
    const short* __restrict__ Hh, const short* __restrict__ Hl,
    float* __restrict__ Pall)
{
    extern __shared__ short sm[];
    short* Asm = sm;
    short* Wsm = sm + 8192;
    const int b = blockIdx.x, tid = threadIdx.x;
    const int wv = tid >> 6, l = tid & 63;
    const int gl = l >> 4, cc = l & 15;

    const int arow = ((tid >> 6) & 3) * 16 + (tid & 15);
    const int ag   = (tid >> 4) & 3;
    const short* qhp = Qh + ((long)arow * BATCH + b) * HID + ag * 8;
    const short* qlp = Ql + ((long)arow * BATCH + b) * HID + ag * 8;
    const int aLds = tid * 8;

    const short *whp[2], *wlp[2]; int wLds[2];
    #pragma unroll
    for (int i = 0; i < 2; ++i) {
        const int s = tid + i * 256;
        const int srow = ((s >> 6) & 7) * 16 + (s & 15);
        const int sg   = (s >> 4) & 3;
        whp[i] = Hh + ((long)srow * BATCH + b) * HID + sg * 8;
        wlp[i] = Hl + ((long)srow * BATCH + b) * HID + sg * 8;
        wLds[i] = s * 8;
    }

    f32x4 acc[8];
    #pragma unroll
    for (int i = 0; i < 8; ++i) acc[i] = (f32x4)0.f;

    short8 rAh, rAl, rWh[2], rWl[2];
    auto LOADC = [&](int c) {
        rAh = *(const short8*)(qhp + c * 32);
        rAl = *(const short8*)(qlp + c * 32);
        #pragma unroll
        for (int i = 0; i < 2; ++i) {
            rWh[i] = *(const short8*)(whp[i] + c * 32);
            rWl[i] = *(const short8*)(wlp[i] + c * 32);
        }
    };
    auto STORE = [&](int c) {
        const int bb = c & 1;
        *(short8*)(Asm + bb * 4096 + aLds) = rAh;
        *(short8*)(Asm + bb * 4096 + 2048 + aLds) = rAl;
        #pragma unroll
        for (int i = 0; i < 2; ++i) {
            *(short8*)(Wsm + bb * 8192 + wLds[i]) = rWh[i];
            *(short8*)(Wsm + bb * 8192 + 4096 + wLds[i]) = rWl[i];
        }
    };

    LOADC(0); STORE(0); LOADC(1);
    __syncthreads();
    for (int c = 0; c < 32; ++c) {
        const int bb = c & 1;
        const short* abp = Asm + bb * 4096 + (wv * 64 + l) * 8;
        short8 ah = *(const short8*)abp;
        short8 al = *(const short8*)(abp + 2048);
        if (c + 1 < 32) STORE(c + 1);
        if (c + 2 < 32) LOADC(c + 2);
        #pragma unroll
        for (int jt = 0; jt < 8; ++jt) {
            const short* wbp = Wsm + bb * 8192 + (jt * 64 + l) * 8;
            short8 wh = *(const short8*)wbp;
            short8 wl = *(const short8*)(wbp + 4096);
            TRI(ah, al, wh, wl, acc[jt]);
        }
        __syncthreads();
    }

    #pragma unroll
    for (int reg = 0; reg < 4; ++reg) {
        float m = acc[0][reg];
        #pragma unroll
        for (int jt = 1; jt < 8; ++jt) m = fmaxf(m, acc[jt][reg]);
        #pragma unroll
        for (int off = 1; off < 16; off <<= 1) m = fmaxf(m, __shfl_xor(m, off));
        float e[8], ssum = 0.f;
        #pragma unroll
        for (int jt = 0; jt < 8; ++jt) { e[jt] = __expf(acc[jt][reg] - m); ssum += e[jt]; }
        #pragma unroll
        for (int off = 1; off < 16; off <<= 1) ssum += __shfl_xor(ssum, off);
        const float inv = 1.f / ssum;
        const int t = wv * 16 + gl * 4 + reg;
        #pragma unroll
        for (int jt = 0; jt < 8; ++jt)
            Pall[((long)t * BATCH + b) * SLEN + jt * 16 + cc] = e[jt] * inv;
    }
}

__global__ __launch_bounds__(256) void ctx_k(
    const float* __restrict__ Pall, const float* __restrict__ H,
    short* __restrict__ Ch, short* __restrict__ Cl)
{
    __shared__ float Ps[T_STEPS * SLEN];
    const int b = blockIdx.x, ht = blockIdx.y, tid = threadIdx.x;
    for (int i = 0; i < 32; ++i) {
        const int idx = i * 256 + tid;
        const int t = idx >> 7, s = idx & 127;
        Ps[idx] = Pall[((long)t * BATCH + b) * SLEN + s];
    }
    __syncthreads();
    const int col = ht * 256 + tid;
    for (int tg = 0; tg < 4; ++tg) {
        float a[16];
        #pragma unroll
        for (int j = 0; j < 16; ++j) a[j] = 0.f;
        for (int s = 0; s < SLEN; ++s) {
            const float hv = H[((long)s * BATCH + b) * HID + col];
            #pragma unroll
            for (int j = 0; j < 16; ++j)
                a[j] = fmaf(Ps[(tg * 16 + j) * SLEN + s], hv, a[j]);
        }
        #pragma unroll
        for (int j = 0; j < 16; ++j) {
            const long row = (long)(tg * 16 + j) * BATCH + b;
            const unsigned short hi = f2bf(a[j]);
            const unsigned short lo = f2bf(a[j] - bf2f(hi));
            Ch[row * HID + col] = (short)hi;
            Cl[row * HID + col] = (short)lo;
        }
    }
}

// =========================== launch ===========================
extern "C" void kernel_launch(void* const* d_in, const int* in_sizes, int n_in,
                              void* d_out, int out_size, void* d_ws, size_t ws_size,
                              hipStream_t stream)
{
    const int*   input = (const int*)  d_in[0];
    const float* h_in  = (const float*)d_in[1];
    const float* Hbuf  = (const float*)d_in[2];
    const float* emb   = (const float*)d_in[3];
    const float* w_ih  = (const float*)d_in[4];
    const float* w_hh  = (const float*)d_in[5];
    const float* b_ih  = (const float*)d_in[6];
    const float* b_hh  = (const float*)d_in[7];
    const float* L1    = (const float*)d_in[8];
    const float* L2    = (const float*)d_in[9];

    float* out = (float*)d_out;

    char* basep = (char*)d_ws;
    size_t off = 0;
    auto alloc = [&](size_t bytes) -> char* {
        off = (off + 255) & ~(size_t)255;
        char* p = basep + off; off += bytes; return p;
    };
    short* wihH = (short*)alloc(2L*3072*1024*2); short* wihL = (short*)alloc(2L*3072*1024*2);
    short* whhH = (short*)alloc(2L*3072*1024*2); short* whhL = (short*)alloc(2L*3072*1024*2);
    short* l1h  = (short*)alloc(1024L*1024*2);   short* l1l  = (short*)alloc(1024L*1024*2);
    short* l2h  = (short*)alloc(1024L*2048*2);   short* l2l  = (short*)alloc(1024L*2048*2);
    short* Hh   = (short*)alloc(16777216L*2);    short* Hl   = (short*)alloc(16777216L*2);
    short* hih  = (short*)alloc(262144L*2);      short* hil  = (short*)alloc(262144L*2);
    short* h0ah = (short*)alloc(8388608L*2);     short* h0al = (short*)alloc(8388608L*2);
    short* h1ah = (short*)alloc(8388608L*2);     short* h1al = (short*)alloc(8388608L*2);
    short* eqh  = (short*)alloc(8388608L*2);     short* eql  = (short*)alloc(8388608L*2);
    float* gi0  = (float*)alloc(25165824L*4);
    float* h0f  = (float*)alloc(524288L*4);
    float* h1f  = (float*)alloc(524288L*4);
    float* Pall = (float*)alloc(1048576L*4);
    short* ctxh = (short*)gi0;                   // gi0 dead after recurrence
    short* ctxl = ctxh + 8388608L;

    const short* wih0h = wihH;
    const short* wih0l = wihL;
    const short* wih1h = wihH + 3145728L;
    const short* wih1l = wihL + 3145728L;
    const short* whh0h = whhH;
    const short* whh1h = whhH + 3145728L;

    const dim3 blk(256);
    const size_t SMB = 32768 * sizeof(short);   // 64 KB for gemm_big

    // ---- phase 0: plane conversions ----
    conv_planes_k<<<3072, blk, 0, stream>>>(w_ih, wihH, wihL);
    conv_planes_k<<<3072, blk, 0, stream>>>(w_hh, whhH, whhL);
    conv_planes_k<<<512,  blk, 0, stream>>>(L1, l1h, l1l);
    conv_planes_k<<<1024, blk, 0, stream>>>(L2, l2h, l2l);
    conv_planes_k<<<8192, blk, 0, stream>>>(Hbuf, Hh, Hl);
    conv_planes_k<<<128,  blk, 0, stream>>>(h_in, hih, hil);
    conv_gather_k<<<4096, blk, 0, stream>>>(emb, input, eqh, eql);

    // gi0_all = E @ w_ih0^T + b_ih0   (8192 x 3072 x 1024), WLO
    gemm_big<0, false, true><<<dim3(1536), blk, SMB, stream>>>(
        eqh, eql, nullptr, nullptr, wih0h, wih0l, 1024, 24,
        b_ih, gi0, nullptr, nullptr, H3);

    // ---- pipelined recurrence: 65 launches, 512 blocks each ----
    StepP sp;
    sp.hih = hih; sp.hil = hil; sp.h_in = h_in; sp.gi0 = gi0;
    sp.whh0h = whh0h;
    sp.wih1h = wih1h; sp.wih1l = wih1l; sp.whh1h = whh1h;
    sp.b_hh0 = b_hh; sp.b_ih1 = b_ih + H3; sp.b_hh1 = b_hh + H3;
    sp.h0f = h0f; sp.h1f = h1f;
    sp.h0ah = h0ah; sp.h0al = h0al; sp.h1ah = h1ah; sp.h1al = h1al;
    for (int t = 0; t <= T_STEPS; ++t)
        step_k<<<dim3(4, 64, 2), blk, 0, stream>>>(t, sp);

    // ---- batched attention + output ----
    gemm_big<1, false, false><<<dim3(512), blk, SMB, stream>>>(
        h1ah, h1al, nullptr, nullptr, l1h, l1l, 1024, 8,
        nullptr, nullptr, eqh, eql, HID);
    scores_k<<<dim3(BATCH), blk, 49152, stream>>>(eqh, eql, Hh, Hl, Pall);
    ctx_k<<<dim3(BATCH, 4), blk, 0, stream>>>(Pall, Hbuf, ctxh, ctxl);
    gemm_big<2, true, false><<<dim3(512), blk, SMB, stream>>>(
        ctxh, ctxl, h1ah, h1al, l2h, l2l, 2048, 8,
        nullptr, out, nullptr, nullptr, HID);

    hipMemcpyAsync(out + (long)T_STEPS * BH, h0f + BH, (size_t)BH * 4,
                   hipMemcpyDeviceToDevice, stream);
    hipMemcpyAsync(out + (long)T_STEPS * BH + BH, h1f + BH, (size_t)BH * 4,
                   hipMemcpyDeviceToDevice, stream);
}